// Round 8
// baseline (392.979 us; speedup 1.0000x reference)
//
#include <hip/hip_runtime.h>
#include <stdint.h>

// Binary conv + BN + sign + ReLU, MI355X (gfx950).
// v3 (resubmit x3): v2.1 + __launch_bounds__(128,2) on bconv_fast so the
// 72-word activation window stays VGPR-resident (v2.1 measured VGPR_Count=52
// -> window was re-read from LDS every co-iteration), + unroll 2 on the
// co-loop to pipeline the scalar weight loads under the popcount VALU work.

#define CH   256
#define HH   56
#define WW   56
#define HWSZ (HH*WW)          // 3136
#define NBATCH 32
#define NHW  (NBATCH*HWSZ)    // 100352

// ---------------- workspace layout (bytes) ----------------
// stats @0       : float2[256]                2048
// flags @2048    : uint32
// corr  @4096    : int32[256*9]               9216
// Wsign @16384   : uint32[256*72]             73728
// Wmask @90112   : uint32[256*72]             73728
// Apack @163840  : u64[32*56*56*4]            3211264   (psum/psum2 alias here pre-binarize)
// Amask @3375104 : u64[32*56*56*4]            3211264

// ---------------- kernel 1a: per-(c,n)-plane partial sums ----------------
__global__ __launch_bounds__(256) void bn_partial(const float* __restrict__ x,
                                                  double* __restrict__ psum,
                                                  double* __restrict__ psum2) {
    int b = blockIdx.x;          // b = c*32 + n
    int c = b >> 5, n = b & 31;
    const float4* x4 = (const float4*)x + (size_t)(n * CH + c) * 784;
    double s = 0.0, s2 = 0.0;
    for (int i = threadIdx.x; i < 784; i += 256) {
        float4 v = x4[i];
        s  += (double)v.x + (double)v.y + (double)v.z + (double)v.w;
        s2 += (double)v.x * v.x + (double)v.y * v.y
            + (double)v.z * v.z + (double)v.w * v.w;
    }
    for (int o = 32; o > 0; o >>= 1) {
        s  += __shfl_down(s, o);
        s2 += __shfl_down(s2, o);
    }
    __shared__ double ls[4], ls2[4];
    int wv = threadIdx.x >> 6, lane = threadIdx.x & 63;
    if (lane == 0) { ls[wv] = s; ls2[wv] = s2; }
    __syncthreads();
    if (threadIdx.x == 0) {
        psum[b]  = ls[0] + ls[1] + ls[2] + ls[3];
        psum2[b] = ls2[0] + ls2[1] + ls2[2] + ls2[3];
    }
}

// ---------------- kernel 1b: finalize stats, zero flags ----------------
__global__ __launch_bounds__(256) void bn_final(const double* __restrict__ psum,
                                                const double* __restrict__ psum2,
                                                float* __restrict__ stats,
                                                unsigned* __restrict__ flags) {
    int c = threadIdx.x;
    double s = 0.0, s2 = 0.0;
    for (int n = 0; n < 32; ++n) { s += psum[c * 32 + n]; s2 += psum2[c * 32 + n]; }
    double mean = s / (double)NHW;
    double var  = s2 / (double)NHW - mean * mean;
    double istd = 1.0 / sqrt(var + 1e-5);
    stats[2 * c]     = (float)mean;
    stats[2 * c + 1] = (float)istd;
    if (c == 0) *flags = 0u;
}

// ---------------- kernel 2: binarize + bit-pack ----------------
__global__ __launch_bounds__(256) void binarize(const float* __restrict__ x,
                                                const float* __restrict__ gamma,
                                                const float* __restrict__ beta,
                                                const float* __restrict__ stats,
                                                unsigned long long* __restrict__ Apack,
                                                unsigned long long* __restrict__ Amask,
                                                unsigned* __restrict__ flags) {
    int b = blockIdx.x;
    int n = b / HH, h = b - n * HH;
    __shared__ float lds[CH][57];
    __shared__ __align__(16) unsigned long long pb[WW][4], mb[WW][4];
    const float4* x4 = (const float4*)x;
    for (int i = threadIdx.x; i < CH * 14; i += 256) {
        int ci = i / 14, jj = i - ci * 14;
        float4 v = x4[(size_t)(n * CH + ci) * 784 + h * 14 + jj];
        lds[ci][jj * 4 + 0] = v.x;
        lds[ci][jj * 4 + 1] = v.y;
        lds[ci][jj * 4 + 2] = v.z;
        lds[ci][jj * 4 + 3] = v.w;
    }
    __syncthreads();
    int ci = threadIdx.x, wv = ci >> 6, lane = ci & 63;
    float m = stats[2 * ci], istd = stats[2 * ci + 1];
    float g = gamma[ci], be = beta[ci];
    bool anyz = false;
    #pragma unroll 4
    for (int w = 0; w < WW; ++w) {
        float t  = (lds[ci][w] - m) * istd;
        float xn = t * g + be;
        unsigned long long sb  = __ballot(xn > 0.0f);
        unsigned long long mbv = __ballot(xn != 0.0f);
        anyz |= (xn == 0.0f);
        if (lane == 0) { pb[w][wv] = sb; mb[w][wv] = mbv; }
    }
    if (__any(anyz) && lane == 0) atomicOr(flags, 1u);
    __syncthreads();
    const uint4* ps = (const uint4*)&pb[0][0];
    const uint4* pm = (const uint4*)&mb[0][0];
    uint4* go = (uint4*)(Apack + (size_t)b * 224);
    uint4* gm = (uint4*)(Amask + (size_t)b * 224);
    for (int i = threadIdx.x; i < 112; i += 256) go[i] = ps[i];
    for (int i = threadIdx.x; i < 112; i += 256) gm[i] = pm[i];
}

// ---------------- kernel 3: pack weights + border-corr table ----------------
__global__ __launch_bounds__(128) void packw(const float* __restrict__ wt,
                                             uint32_t* __restrict__ Wsign,
                                             uint32_t* __restrict__ Wmask,
                                             int* __restrict__ corr,
                                             unsigned* __restrict__ flags) {
    int co = blockIdx.x, t = threadIdx.x;
    __shared__ int wpc[72];
    if (t < 72) {
        int tap = t >> 3, word = t & 7;
        unsigned sb = 0u, mbv = 0u;
        for (int j = 0; j < 32; ++j) {
            float v = wt[((size_t)co * CH + (word * 32 + j)) * 9 + tap];
            sb  |= (v > 0.0f ? 1u : 0u) << j;
            mbv |= (v != 0.0f ? 1u : 0u) << j;
        }
        Wsign[co * 72 + tap * 8 + word] = sb;
        Wmask[co * 72 + tap * 8 + word] = mbv;
        wpc[tap * 8 + word] = __popc(sb);
        if (mbv != 0xffffffffu) atomicOr(flags, 2u);
    }
    __syncthreads();
    if (t < 9) {
        int cfgH = t / 3, cfgW = t % 3;
        int s = 0;
        for (int tap = 0; tap < 9; ++tap) {
            int kh = tap / 3, kw = tap % 3;
            bool inv = (cfgH == 1 && kh == 0) || (cfgH == 2 && kh == 2) ||
                       (cfgW == 1 && kw == 0) || (cfgW == 2 && kw == 2);
            if (inv) {
                int p = 0;
                for (int k = 0; k < 8; ++k) p += wpc[tap * 8 + k];
                s += 256 - 2 * p;
            }
        }
        corr[co * 9 + t] = s;
    }
}

// ---------------- kernel 4: fast binary conv ----------------
// thread = pixel (128/block, min 2 waves/EU -> up to 256 VGPR budget so the
// 72-word window stays register-resident), loop co with unroll 2 so the
// next pair's s_load weights issue under the current popcount work.
__global__ __launch_bounds__(128, 2) void bconv_fast(const uint32_t* __restrict__ Apack,
                                                     const uint32_t* __restrict__ Wsign,
                                                     const int* __restrict__ corr,
                                                     const float* __restrict__ bias,
                                                     const unsigned* __restrict__ flags,
                                                     float* __restrict__ out) {
    if (*flags != 0u) return;   // exact-zero fallback handled by bconv_slow
    __shared__ __align__(16) uint32_t As[6][58][8];   // zero-padded cols 0,57
    __shared__ int corr_lds[2304];
    __shared__ float bias_lds[CH];
    int bb = blockIdx.x;
    int cs = bb & 1;
    int b  = bb >> 1;
    int n  = b / 25, pt = b % 25;
    int pix0 = pt * 128;
    int pix  = pix0 + threadIdx.x;
    bool valid = pix < HWSZ;
    int pixc = valid ? pix : HWSZ - 1;
    int h = pixc / WW, w = pixc - h * WW;
    int h0 = pix0 / WW;

    // stage 6 activation rows (h0-1 .. h0+4), zero-padded cols
    const uint4* Ap4 = (const uint4*)Apack + (size_t)n * (HWSZ * 2);
    for (int i = threadIdx.x; i < 696; i += 128) {
        int r = i / 116, j = i - r * 116;
        int col = j >> 1, half = j & 1;
        int gr = h0 - 1 + r;
        uint4 val = make_uint4(0u, 0u, 0u, 0u);
        if (gr >= 0 && gr < HH && col >= 1 && col <= WW)
            val = Ap4[(gr * WW + (col - 1)) * 2 + half];
        *(uint4*)&As[r][col][half * 4] = val;
    }
    for (int i = threadIdx.x; i < 576; i += 128)
        ((uint4*)corr_lds)[i] = ((const uint4*)corr)[i];
    for (int i = threadIdx.x; i < CH; i += 128)
        bias_lds[i] = bias[i];
    __syncthreads();

    // load this pixel's 3x3x256-bit window into VGPRs (reused for all co)
    uint32_t win[72];
    int lh = h - h0;
    #pragma unroll
    for (int kh = 0; kh < 3; ++kh) {
        #pragma unroll
        for (int kw = 0; kw < 3; ++kw) {
            const uint4* p = (const uint4*)&As[lh + kh][w + kw][0];
            uint4 lo = p[0], hi = p[1];
            int t = (kh * 3 + kw) * 8;
            win[t + 0] = lo.x; win[t + 1] = lo.y; win[t + 2] = lo.z; win[t + 3] = lo.w;
            win[t + 4] = hi.x; win[t + 5] = hi.y; win[t + 6] = hi.z; win[t + 7] = hi.w;
        }
    }
    int cfg = ((h == 0) ? 1 : (h == HH - 1) ? 2 : 0) * 3
            + ((w == 0) ? 1 : (w == WW - 1) ? 2 : 0);
    size_t obase = (size_t)n * (CH * HWSZ) + pix;
    int co0 = cs * 128;
    #pragma unroll 2
    for (int coi = 0; coi < 128; ++coi) {
        int co = co0 + coi;
        const uint32_t* wp = Wsign + co * 72;   // uniform address -> s_load
        int a0 = 0, a1 = 0, a2 = 0, a3 = 0;
        #pragma unroll
        for (int i = 0; i < 72; i += 4) {
            a0 += __popc(win[i + 0] ^ wp[i + 0]);
            a1 += __popc(win[i + 1] ^ wp[i + 1]);
            a2 += __popc(win[i + 2] ^ wp[i + 2]);
            a3 += __popc(win[i + 3] ^ wp[i + 3]);
        }
        int ival = 2304 - 2 * ((a0 + a1) + (a2 + a3)) - corr_lds[co * 9 + cfg];
        float o = (float)ival + bias_lds[co];
        o = o > 0.0f ? o : 0.0f;
        if (valid) out[obase + (size_t)co * HWSZ] = o;
    }
}

// ---------------- kernel 5: exact ternary fallback (runs only if zeros exist) ----------------
__global__ __launch_bounds__(256) void bconv_slow(const uint32_t* __restrict__ Apack,
                                                  const uint32_t* __restrict__ Amask,
                                                  const uint32_t* __restrict__ Wsign,
                                                  const uint32_t* __restrict__ Wmask,
                                                  const float* __restrict__ bias,
                                                  const unsigned* __restrict__ flags,
                                                  float* __restrict__ out) {
    if (*flags == 0u) return;
    int b = blockIdx.x;
    int n = b / 28, tb = b - n * 28;
    int h0 = tb * 2;
    int co = threadIdx.x;
    __shared__ __align__(16) uint32_t As[4][WW][8];
    __shared__ __align__(16) uint32_t Am[4][WW][8];
    int rlo = max(h0 - 1, 0), rhi = min(h0 + 2, HH - 1);
    int nw = (rhi - rlo + 1) * WW * 8;
    {
        const uint4* s4  = (const uint4*)(Apack + (size_t)(n * HH + rlo) * WW * 8);
        const uint4* s4m = (const uint4*)(Amask + (size_t)(n * HH + rlo) * WW * 8);
        uint4* d4  = (uint4*)&As[rlo - (h0 - 1)][0][0];
        uint4* d4m = (uint4*)&Am[rlo - (h0 - 1)][0][0];
        for (int i = threadIdx.x; i < nw / 4; i += 256) { d4[i] = s4[i]; d4m[i] = s4m[i]; }
    }
    uint32_t wreg[72];
    #pragma unroll
    for (int i = 0; i < 72; ++i) wreg[i] = Wsign[co * 72 + i];
    float bi = bias[co];
    __syncthreads();
    for (int r = 0; r < 2; ++r) {
        int h = h0 + r;
        size_t obase = (size_t)(n * CH + co) * HWSZ + (size_t)h * WW;
        for (int c = 0; c < WW; ++c) {
            int acc = 0, kcnt = 0;
            #pragma unroll
            for (int kh = 0; kh < 3; ++kh) {
                int hh = h - 1 + kh;
                if (hh < 0 || hh >= HH) continue;
                int lr = r + kh;
                #pragma unroll
                for (int kw = 0; kw < 3; ++kw) {
                    int wwc = c - 1 + kw;
                    if (wwc < 0 || wwc >= WW) continue;
                    const uint32_t* ap = &As[lr][wwc][0];
                    const uint32_t* am = &Am[lr][wwc][0];
                    const uint32_t* wm = Wmask + (co * 9 + kh * 3 + kw) * 8;
                    #pragma unroll
                    for (int k = 0; k < 8; ++k) {
                        uint32_t M = am[k] & wm[k];
                        kcnt += __popc(M);
                        acc  += __popc((ap[k] ^ wreg[(kh * 3 + kw) * 8 + k]) & M);
                    }
                }
            }
            float o = (float)(kcnt - 2 * acc) + bi;
            out[obase + c] = o > 0.0f ? o : 0.0f;
        }
    }
}

extern "C" void kernel_launch(void* const* d_in, const int* in_sizes, int n_in,
                              void* d_out, int out_size, void* d_ws, size_t ws_size,
                              hipStream_t stream) {
    const float* x     = (const float*)d_in[0];
    const float* gamma = (const float*)d_in[1];
    const float* beta  = (const float*)d_in[2];
    const float* wt    = (const float*)d_in[3];
    const float* bias  = (const float*)d_in[4];
    float* out = (float*)d_out;

    char* ws = (char*)d_ws;
    float*    stats = (float*)(ws);
    unsigned* flags = (unsigned*)(ws + 2048);
    int*      corr  = (int*)(ws + 4096);
    uint32_t* Wsign = (uint32_t*)(ws + 16384);
    uint32_t* Wmask = (uint32_t*)(ws + 90112);
    uint32_t* Apack = (uint32_t*)(ws + 163840);
    uint32_t* Amask = (uint32_t*)(ws + 3375104);
    // psum/psum2 alias the Apack region (consumed by bn_final before binarize writes it)
    double*   psum  = (double*)(ws + 163840);
    double*   psum2 = (double*)(ws + 163840 + 65536);

    hipLaunchKernelGGL(bn_partial, dim3(8192), dim3(256), 0, stream, x, psum, psum2);
    hipLaunchKernelGGL(bn_final, dim3(1), dim3(256), 0, stream, psum, psum2, stats, flags);
    hipLaunchKernelGGL(binarize, dim3(NBATCH * HH), dim3(256), 0, stream,
                       x, gamma, beta, stats,
                       (unsigned long long*)Apack, (unsigned long long*)Amask, flags);
    hipLaunchKernelGGL(packw, dim3(256), dim3(128), 0, stream, wt, Wsign, Wmask, corr, flags);
    hipLaunchKernelGGL(bconv_fast, dim3(1600), dim3(128), 0, stream,
                       Apack, Wsign, corr, bias, flags, out);
    hipLaunchKernelGGL(bconv_slow, dim3(NBATCH * 28), dim3(256), 0, stream,
                       Apack, Amask, Wsign, Wmask, bias, flags, out);
}

// Round 12
// 391.247 us; speedup vs baseline: 1.0044x; 1.0044x over previous
//
#include <hip/hip_runtime.h>
#include <stdint.h>

// Binary conv + BN + sign + ReLU, MI355X (gfx950).
// v4 (resubmit x3): v3 + asm-pin of the 72-word activation window into VGPRs.
// v3 post-mortem: __launch_bounds__(128,2) did NOT stop the compiler from
// re-reading the window from LDS every co-iteration (VGPR stayed 52; LLVM
// remat heuristic treats LDS loads as free). That re-read is 7.4 TB of LDS
// traffic (~107us at 69 TB/s) and is the measured bottleneck (168us, VALU 60%).
// asm volatile("" : "+v") makes each window word opaque -> must stay in VGPR.

#define CH   256
#define HH   56
#define WW   56
#define HWSZ (HH*WW)          // 3136
#define NBATCH 32
#define NHW  (NBATCH*HWSZ)    // 100352

// ---------------- workspace layout (bytes) ----------------
// stats @0       : float2[256]                2048
// flags @2048    : uint32
// corr  @4096    : int32[256*9]               9216
// Wsign @16384   : uint32[256*72]             73728
// Wmask @90112   : uint32[256*72]             73728
// Apack @163840  : u64[32*56*56*4]            3211264   (psum/psum2 alias here pre-binarize)
// Amask @3375104 : u64[32*56*56*4]            3211264

// ---------------- kernel 1a: per-(c,n)-plane partial sums ----------------
__global__ __launch_bounds__(256) void bn_partial(const float* __restrict__ x,
                                                  double* __restrict__ psum,
                                                  double* __restrict__ psum2) {
    int b = blockIdx.x;          // b = c*32 + n
    int c = b >> 5, n = b & 31;
    const float4* x4 = (const float4*)x + (size_t)(n * CH + c) * 784;
    double s = 0.0, s2 = 0.0;
    for (int i = threadIdx.x; i < 784; i += 256) {
        float4 v = x4[i];
        s  += (double)v.x + (double)v.y + (double)v.z + (double)v.w;
        s2 += (double)v.x * v.x + (double)v.y * v.y
            + (double)v.z * v.z + (double)v.w * v.w;
    }
    for (int o = 32; o > 0; o >>= 1) {
        s  += __shfl_down(s, o);
        s2 += __shfl_down(s2, o);
    }
    __shared__ double ls[4], ls2[4];
    int wv = threadIdx.x >> 6, lane = threadIdx.x & 63;
    if (lane == 0) { ls[wv] = s; ls2[wv] = s2; }
    __syncthreads();
    if (threadIdx.x == 0) {
        psum[b]  = ls[0] + ls[1] + ls[2] + ls[3];
        psum2[b] = ls2[0] + ls2[1] + ls2[2] + ls2[3];
    }
}

// ---------------- kernel 1b: finalize stats, zero flags ----------------
__global__ __launch_bounds__(256) void bn_final(const double* __restrict__ psum,
                                                const double* __restrict__ psum2,
                                                float* __restrict__ stats,
                                                unsigned* __restrict__ flags) {
    int c = threadIdx.x;
    double s = 0.0, s2 = 0.0;
    for (int n = 0; n < 32; ++n) { s += psum[c * 32 + n]; s2 += psum2[c * 32 + n]; }
    double mean = s / (double)NHW;
    double var  = s2 / (double)NHW - mean * mean;
    double istd = 1.0 / sqrt(var + 1e-5);
    stats[2 * c]     = (float)mean;
    stats[2 * c + 1] = (float)istd;
    if (c == 0) *flags = 0u;
}

// ---------------- kernel 2: binarize + bit-pack ----------------
__global__ __launch_bounds__(256) void binarize(const float* __restrict__ x,
                                                const float* __restrict__ gamma,
                                                const float* __restrict__ beta,
                                                const float* __restrict__ stats,
                                                unsigned long long* __restrict__ Apack,
                                                unsigned long long* __restrict__ Amask,
                                                unsigned* __restrict__ flags) {
    int b = blockIdx.x;
    int n = b / HH, h = b - n * HH;
    __shared__ float lds[CH][57];
    __shared__ __align__(16) unsigned long long pb[WW][4], mb[WW][4];
    const float4* x4 = (const float4*)x;
    for (int i = threadIdx.x; i < CH * 14; i += 256) {
        int ci = i / 14, jj = i - ci * 14;
        float4 v = x4[(size_t)(n * CH + ci) * 784 + h * 14 + jj];
        lds[ci][jj * 4 + 0] = v.x;
        lds[ci][jj * 4 + 1] = v.y;
        lds[ci][jj * 4 + 2] = v.z;
        lds[ci][jj * 4 + 3] = v.w;
    }
    __syncthreads();
    int ci = threadIdx.x, wv = ci >> 6, lane = ci & 63;
    float m = stats[2 * ci], istd = stats[2 * ci + 1];
    float g = gamma[ci], be = beta[ci];
    bool anyz = false;
    #pragma unroll 4
    for (int w = 0; w < WW; ++w) {
        float t  = (lds[ci][w] - m) * istd;
        float xn = t * g + be;
        unsigned long long sb  = __ballot(xn > 0.0f);
        unsigned long long mbv = __ballot(xn != 0.0f);
        anyz |= (xn == 0.0f);
        if (lane == 0) { pb[w][wv] = sb; mb[w][wv] = mbv; }
    }
    if (__any(anyz) && lane == 0) atomicOr(flags, 1u);
    __syncthreads();
    const uint4* ps = (const uint4*)&pb[0][0];
    const uint4* pm = (const uint4*)&mb[0][0];
    uint4* go = (uint4*)(Apack + (size_t)b * 224);
    uint4* gm = (uint4*)(Amask + (size_t)b * 224);
    for (int i = threadIdx.x; i < 112; i += 256) go[i] = ps[i];
    for (int i = threadIdx.x; i < 112; i += 256) gm[i] = pm[i];
}

// ---------------- kernel 3: pack weights + border-corr table ----------------
__global__ __launch_bounds__(128) void packw(const float* __restrict__ wt,
                                             uint32_t* __restrict__ Wsign,
                                             uint32_t* __restrict__ Wmask,
                                             int* __restrict__ corr,
                                             unsigned* __restrict__ flags) {
    int co = blockIdx.x, t = threadIdx.x;
    __shared__ int wpc[72];
    if (t < 72) {
        int tap = t >> 3, word = t & 7;
        unsigned sb = 0u, mbv = 0u;
        for (int j = 0; j < 32; ++j) {
            float v = wt[((size_t)co * CH + (word * 32 + j)) * 9 + tap];
            sb  |= (v > 0.0f ? 1u : 0u) << j;
            mbv |= (v != 0.0f ? 1u : 0u) << j;
        }
        Wsign[co * 72 + tap * 8 + word] = sb;
        Wmask[co * 72 + tap * 8 + word] = mbv;
        wpc[tap * 8 + word] = __popc(sb);
        if (mbv != 0xffffffffu) atomicOr(flags, 2u);
    }
    __syncthreads();
    if (t < 9) {
        int cfgH = t / 3, cfgW = t % 3;
        int s = 0;
        for (int tap = 0; tap < 9; ++tap) {
            int kh = tap / 3, kw = tap % 3;
            bool inv = (cfgH == 1 && kh == 0) || (cfgH == 2 && kh == 2) ||
                       (cfgW == 1 && kw == 0) || (cfgW == 2 && kw == 2);
            if (inv) {
                int p = 0;
                for (int k = 0; k < 8; ++k) p += wpc[tap * 8 + k];
                s += 256 - 2 * p;
            }
        }
        corr[co * 9 + t] = s;
    }
}

// ---------------- kernel 4: fast binary conv ----------------
// thread = pixel, loop co. Weights wave-uniform -> SGPR s_loads. The 72-word
// activation window is asm-pinned into VGPRs (compiler otherwise rematerializes
// it as per-iteration LDS reads -> 7.4 TB LDS traffic, the v2/v3 bottleneck).
__global__ __launch_bounds__(128, 2) void bconv_fast(const uint32_t* __restrict__ Apack,
                                                     const uint32_t* __restrict__ Wsign,
                                                     const int* __restrict__ corr,
                                                     const float* __restrict__ bias,
                                                     const unsigned* __restrict__ flags,
                                                     float* __restrict__ out) {
    if (*flags != 0u) return;   // exact-zero fallback handled by bconv_slow
    __shared__ __align__(16) uint32_t As[6][58][8];   // zero-padded cols 0,57
    __shared__ int corr_lds[2304];
    __shared__ float bias_lds[CH];
    int bb = blockIdx.x;
    int cs = bb & 1;
    int b  = bb >> 1;
    int n  = b / 25, pt = b % 25;
    int pix0 = pt * 128;
    int pix  = pix0 + threadIdx.x;
    bool valid = pix < HWSZ;
    int pixc = valid ? pix : HWSZ - 1;
    int h = pixc / WW, w = pixc - h * WW;
    int h0 = pix0 / WW;

    // stage 6 activation rows (h0-1 .. h0+4), zero-padded cols
    const uint4* Ap4 = (const uint4*)Apack + (size_t)n * (HWSZ * 2);
    for (int i = threadIdx.x; i < 696; i += 128) {
        int r = i / 116, j = i - r * 116;
        int col = j >> 1, half = j & 1;
        int gr = h0 - 1 + r;
        uint4 val = make_uint4(0u, 0u, 0u, 0u);
        if (gr >= 0 && gr < HH && col >= 1 && col <= WW)
            val = Ap4[(gr * WW + (col - 1)) * 2 + half];
        *(uint4*)&As[r][col][half * 4] = val;
    }
    for (int i = threadIdx.x; i < 576; i += 128)
        ((uint4*)corr_lds)[i] = ((const uint4*)corr)[i];
    for (int i = threadIdx.x; i < CH; i += 128)
        bias_lds[i] = bias[i];
    __syncthreads();

    // load this pixel's 3x3x256-bit window into VGPRs (reused for all co)
    uint32_t win[72];
    int lh = h - h0;
    #pragma unroll
    for (int kh = 0; kh < 3; ++kh) {
        #pragma unroll
        for (int kw = 0; kw < 3; ++kw) {
            const uint4* p = (const uint4*)&As[lh + kh][w + kw][0];
            uint4 lo = p[0], hi = p[1];
            int t = (kh * 3 + kw) * 8;
            win[t + 0] = lo.x; win[t + 1] = lo.y; win[t + 2] = lo.z; win[t + 3] = lo.w;
            win[t + 4] = hi.x; win[t + 5] = hi.y; win[t + 6] = hi.z; win[t + 7] = hi.w;
        }
    }
    // Pin every window word into a VGPR: the value becomes asm-defined, so the
    // compiler cannot re-derive it from LDS inside the co-loop (rule-17 trick).
    #pragma unroll
    for (int i = 0; i < 72; ++i) asm volatile("" : "+v"(win[i]));

    int cfg = ((h == 0) ? 1 : (h == HH - 1) ? 2 : 0) * 3
            + ((w == 0) ? 1 : (w == WW - 1) ? 2 : 0);
    size_t obase = (size_t)n * (CH * HWSZ) + pix;
    int co0 = cs * 128;
    #pragma unroll 2
    for (int coi = 0; coi < 128; ++coi) {
        int co = co0 + coi;
        const uint32_t* wp = Wsign + co * 72;   // uniform address -> s_load
        int a0 = 0, a1 = 0, a2 = 0, a3 = 0;
        #pragma unroll
        for (int i = 0; i < 72; i += 4) {
            a0 += __popc(win[i + 0] ^ wp[i + 0]);
            a1 += __popc(win[i + 1] ^ wp[i + 1]);
            a2 += __popc(win[i + 2] ^ wp[i + 2]);
            a3 += __popc(win[i + 3] ^ wp[i + 3]);
        }
        int ival = 2304 - 2 * ((a0 + a1) + (a2 + a3)) - corr_lds[co * 9 + cfg];
        float o = (float)ival + bias_lds[co];
        o = o > 0.0f ? o : 0.0f;
        if (valid) out[obase + (size_t)co * HWSZ] = o;
    }
}

// ---------------- kernel 5: exact ternary fallback (runs only if zeros exist) ----------------
__global__ __launch_bounds__(256) void bconv_slow(const uint32_t* __restrict__ Apack,
                                                  const uint32_t* __restrict__ Amask,
                                                  const uint32_t* __restrict__ Wsign,
                                                  const uint32_t* __restrict__ Wmask,
                                                  const float* __restrict__ bias,
                                                  const unsigned* __restrict__ flags,
                                                  float* __restrict__ out) {
    if (*flags == 0u) return;
    int b = blockIdx.x;
    int n = b / 28, tb = b - n * 28;
    int h0 = tb * 2;
    int co = threadIdx.x;
    __shared__ __align__(16) uint32_t As[4][WW][8];
    __shared__ __align__(16) uint32_t Am[4][WW][8];
    int rlo = max(h0 - 1, 0), rhi = min(h0 + 2, HH - 1);
    int nw = (rhi - rlo + 1) * WW * 8;
    {
        const uint4* s4  = (const uint4*)(Apack + (size_t)(n * HH + rlo) * WW * 8);
        const uint4* s4m = (const uint4*)(Amask + (size_t)(n * HH + rlo) * WW * 8);
        uint4* d4  = (uint4*)&As[rlo - (h0 - 1)][0][0];
        uint4* d4m = (uint4*)&Am[rlo - (h0 - 1)][0][0];
        for (int i = threadIdx.x; i < nw / 4; i += 256) { d4[i] = s4[i]; d4m[i] = s4m[i]; }
    }
    uint32_t wreg[72];
    #pragma unroll
    for (int i = 0; i < 72; ++i) wreg[i] = Wsign[co * 72 + i];
    float bi = bias[co];
    __syncthreads();
    for (int r = 0; r < 2; ++r) {
        int h = h0 + r;
        size_t obase = (size_t)(n * CH + co) * HWSZ + (size_t)h * WW;
        for (int c = 0; c < WW; ++c) {
            int acc = 0, kcnt = 0;
            #pragma unroll
            for (int kh = 0; kh < 3; ++kh) {
                int hh = h - 1 + kh;
                if (hh < 0 || hh >= HH) continue;
                int lr = r + kh;
                #pragma unroll
                for (int kw = 0; kw < 3; ++kw) {
                    int wwc = c - 1 + kw;
                    if (wwc < 0 || wwc >= WW) continue;
                    const uint32_t* ap = &As[lr][wwc][0];
                    const uint32_t* am = &Am[lr][wwc][0];
                    const uint32_t* wm = Wmask + (co * 9 + kh * 3 + kw) * 8;
                    #pragma unroll
                    for (int k = 0; k < 8; ++k) {
                        uint32_t M = am[k] & wm[k];
                        kcnt += __popc(M);
                        acc  += __popc((ap[k] ^ wreg[(kh * 3 + kw) * 8 + k]) & M);
                    }
                }
            }
            float o = (float)(kcnt - 2 * acc) + bi;
            out[obase + c] = o > 0.0f ? o : 0.0f;
        }
    }
}

extern "C" void kernel_launch(void* const* d_in, const int* in_sizes, int n_in,
                              void* d_out, int out_size, void* d_ws, size_t ws_size,
                              hipStream_t stream) {
    const float* x     = (const float*)d_in[0];
    const float* gamma = (const float*)d_in[1];
    const float* beta  = (const float*)d_in[2];
    const float* wt    = (const float*)d_in[3];
    const float* bias  = (const float*)d_in[4];
    float* out = (float*)d_out;

    char* ws = (char*)d_ws;
    float*    stats = (float*)(ws);
    unsigned* flags = (unsigned*)(ws + 2048);
    int*      corr  = (int*)(ws + 4096);
    uint32_t* Wsign = (uint32_t*)(ws + 16384);
    uint32_t* Wmask = (uint32_t*)(ws + 90112);
    uint32_t* Apack = (uint32_t*)(ws + 163840);
    uint32_t* Amask = (uint32_t*)(ws + 3375104);
    // psum/psum2 alias the Apack region (consumed by bn_final before binarize writes it)
    double*   psum  = (double*)(ws + 163840);
    double*   psum2 = (double*)(ws + 163840 + 65536);

    hipLaunchKernelGGL(bn_partial, dim3(8192), dim3(256), 0, stream, x, psum, psum2);
    hipLaunchKernelGGL(bn_final, dim3(1), dim3(256), 0, stream, psum, psum2, stats, flags);
    hipLaunchKernelGGL(binarize, dim3(NBATCH * HH), dim3(256), 0, stream,
                       x, gamma, beta, stats,
                       (unsigned long long*)Apack, (unsigned long long*)Amask, flags);
    hipLaunchKernelGGL(packw, dim3(256), dim3(128), 0, stream, wt, Wsign, Wmask, corr, flags);
    hipLaunchKernelGGL(bconv_fast, dim3(1600), dim3(128), 0, stream,
                       Apack, Wsign, corr, bias, flags, out);
    hipLaunchKernelGGL(bconv_slow, dim3(NBATCH * 28), dim3(256), 0, stream,
                       Apack, Amask, Wsign, Wmask, bias, flags, out);
}